// Round 1
// baseline (354.015 us; speedup 1.0000x reference)
//
#include <hip/hip_runtime.h>
#include <math.h>

#define K_CODES 512
#define DIM 64

// numpy pairwise sum (n=64 path): 8 strided accumulators, sequential adds
// within each, then pairwise tree combine. Contract OFF so products round
// separately from adds (matches np: elementwise square then pairwise sum).
__device__ __forceinline__ float np_pairwise_sumsq(const float* v) {
#pragma clang fp contract(off)
    float p[DIM];
#pragma unroll
    for (int j = 0; j < DIM; ++j) p[j] = v[j] * v[j];
    float r[8];
#pragma unroll
    for (int a = 0; a < 8; ++a) r[a] = p[a];
#pragma unroll
    for (int i = 8; i < DIM; i += 8) {
#pragma unroll
        for (int a = 0; a < 8; ++a) r[a] = r[a] + p[i + a];
    }
    return ((r[0] + r[1]) + (r[2] + r[3])) + ((r[4] + r[5]) + (r[6] + r[7]));
}

__global__ __launch_bounds__(256) void vq_argmin_gather(
    const float* __restrict__ z, const float* __restrict__ cb,
    float* __restrict__ out, int n_rows) {
#pragma clang fp contract(off)
    __shared__ float esq_lds[K_CODES];

    const int t = threadIdx.x;
    // Each of 256 threads computes esq for 2 codes (numpy summation order).
    for (int c = t; c < K_CODES; c += 256) {
        esq_lds[c] = np_pairwise_sumsq(cb + (size_t)c * DIM);
    }
    __syncthreads();

    const int n = blockIdx.x * 256 + t;

    // Load this thread's z row into registers (64 VGPRs).
    float zr[DIM];
    const float4* zp = (const float4*)(z + (size_t)n * DIM);
#pragma unroll
    for (int j = 0; j < DIM / 4; ++j) {
        float4 v = zp[j];
        zr[4 * j + 0] = v.x;
        zr[4 * j + 1] = v.y;
        zr[4 * j + 2] = v.z;
        zr[4 * j + 3] = v.w;
    }
    const float zsq = np_pairwise_sumsq(zr);

    float dmin = INFINITY;
    int best = 0;

    for (int k = 0; k < K_CODES; ++k) {
        const float* __restrict__ ck = cb + (size_t)k * DIM;
        // 8-accumulator fmaf dot: ILP-8 so FMA pipe is issue-bound, and
        // mimics a BLAS-style accumulated-in-f32 K loop.
        float a0 = 0.f, a1 = 0.f, a2 = 0.f, a3 = 0.f;
        float a4 = 0.f, a5 = 0.f, a6 = 0.f, a7 = 0.f;
#pragma unroll
        for (int j = 0; j < DIM; j += 8) {
            a0 = fmaf(zr[j + 0], ck[j + 0], a0);
            a1 = fmaf(zr[j + 1], ck[j + 1], a1);
            a2 = fmaf(zr[j + 2], ck[j + 2], a2);
            a3 = fmaf(zr[j + 3], ck[j + 3], a3);
            a4 = fmaf(zr[j + 4], ck[j + 4], a4);
            a5 = fmaf(zr[j + 5], ck[j + 5], a5);
            a6 = fmaf(zr[j + 6], ck[j + 6], a6);
            a7 = fmaf(zr[j + 7], ck[j + 7], a7);
        }
        const float dot = ((a0 + a1) + (a2 + a3)) + ((a4 + a5) + (a6 + a7));
        // Faithful f32 op order of the reference:
        //   d = (zsq + esq_k) - (2 * dot)
        const float tkv = zsq + esq_lds[k];
        const float m = 2.0f * dot;
        const float d = tkv - m;
        if (d < dmin) {   // strict < : first index wins ties, like np.argmin
            dmin = d;
            best = k;
        }
    }

    // Gather codebook[best] and write both outputs (x_recon, z_quantized).
    const float4* cq = (const float4*)(cb + (size_t)best * DIM);
    float4* o0 = (float4*)(out + (size_t)n * DIM);
    float4* o1 = (float4*)(out + (size_t)n_rows * DIM + (size_t)n * DIM);
#pragma unroll
    for (int j = 0; j < DIM / 4; ++j) {
        float4 v = cq[j];
        o0[j] = v;
        o1[j] = v;
    }
}

extern "C" void kernel_launch(void* const* d_in, const int* in_sizes, int n_in,
                              void* d_out, int out_size, void* d_ws, size_t ws_size,
                              hipStream_t stream) {
    const float* z  = (const float*)d_in[0];   // [N, 64] fp32
    const float* cb = (const float*)d_in[1];   // [512, 64] fp32
    float* out = (float*)d_out;                // [2 * N * 64] fp32

    const int n_rows = in_sizes[0] / DIM;      // 131072
    const int block = 256;
    const int grid = n_rows / block;           // 512

    vq_argmin_gather<<<dim3(grid), dim3(block), 0, stream>>>(z, cb, out, n_rows);
}

// Round 2
// 230.583 us; speedup vs baseline: 1.5353x; 1.5353x over previous
//
#include <hip/hip_runtime.h>
#include <math.h>

#define K_CODES 512
#define DIM 64
#define ROWS_PER_BLOCK 128   // 256 threads: t<128 scan k[0,256), t>=128 scan k[256,512)

// numpy pairwise sum (n=64 path): 8 strided accumulators, sequential adds
// within each, then pairwise tree combine. Contract OFF so products round
// separately from adds (matches np: elementwise square then pairwise sum).
__device__ __forceinline__ float np_pairwise_sumsq(const float* v) {
#pragma clang fp contract(off)
    float p[DIM];
#pragma unroll
    for (int j = 0; j < DIM; ++j) p[j] = v[j] * v[j];
    float r[8];
#pragma unroll
    for (int a = 0; a < 8; ++a) r[a] = p[a];
#pragma unroll
    for (int i = 8; i < DIM; i += 8) {
#pragma unroll
        for (int a = 0; a < 8; ++a) r[a] = r[a] + p[i + a];
    }
    return ((r[0] + r[1]) + (r[2] + r[3])) + ((r[4] + r[5]) + (r[6] + r[7]));
}

// launch_bounds(256, 4): 4 waves/EU -> VGPR cap 128. Kernel needs ~100
// (64 zr + 8 acc + addressing); round-1's bare (256) capped at 52 and
// spilled zr to scratch (VGPR_Count=52, WRITE_SIZE 4x inflated).
__global__ __launch_bounds__(256, 4) void vq_argmin_gather(
    const float* __restrict__ z, const float* __restrict__ cb,
    float* __restrict__ out, int n_rows) {
#pragma clang fp contract(off)
    __shared__ float esq_lds[K_CODES];
    __shared__ float red_d[ROWS_PER_BLOCK];
    __shared__ int   red_b[ROWS_PER_BLOCK];
    __shared__ int   best_lds[ROWS_PER_BLOCK];

    const int t = threadIdx.x;

    // esq for all 512 codes, numpy summation order (2 codes/thread).
    for (int c = t; c < K_CODES; c += 256) {
        esq_lds[c] = np_pairwise_sumsq(cb + (size_t)c * DIM);
    }
    __syncthreads();

    const int tr  = t & (ROWS_PER_BLOCK - 1);            // row within block
    const int row = blockIdx.x * ROWS_PER_BLOCK + tr;
    // k-offset: 0 for threads 0..127, 256 for 128..255. Wave-uniform
    // (wave=64 lanes), but the compiler can't prove it -- readfirstlane
    // forces SGPR so codebook loads stay on the scalar (s_load) path.
    const int k0 = __builtin_amdgcn_readfirstlane((t >> 7) << 8);

    // z row into 64 VGPRs.
    float zr[DIM];
    const float4* zp = (const float4*)(z + (size_t)row * DIM);
#pragma unroll
    for (int j = 0; j < DIM / 4; ++j) {
        float4 v = zp[j];
        zr[4 * j + 0] = v.x;
        zr[4 * j + 1] = v.y;
        zr[4 * j + 2] = v.z;
        zr[4 * j + 3] = v.w;
    }
    const float zsq = np_pairwise_sumsq(zr);

    float dmin = INFINITY;
    int best = k0;

    const float* __restrict__ cbase = cb + (size_t)k0 * DIM;
#pragma unroll 2
    for (int kk = 0; kk < K_CODES / 2; ++kk) {
        const float* __restrict__ ck = cbase + (size_t)kk * DIM;
        // 8-accumulator fmaf dot, tree combine -- IDENTICAL arithmetic to
        // the round-1 kernel that matched np argmin exactly. Do not alter.
        float a0 = 0.f, a1 = 0.f, a2 = 0.f, a3 = 0.f;
        float a4 = 0.f, a5 = 0.f, a6 = 0.f, a7 = 0.f;
#pragma unroll
        for (int j = 0; j < DIM; j += 8) {
            a0 = fmaf(zr[j + 0], ck[j + 0], a0);
            a1 = fmaf(zr[j + 1], ck[j + 1], a1);
            a2 = fmaf(zr[j + 2], ck[j + 2], a2);
            a3 = fmaf(zr[j + 3], ck[j + 3], a3);
            a4 = fmaf(zr[j + 4], ck[j + 4], a4);
            a5 = fmaf(zr[j + 5], ck[j + 5], a5);
            a6 = fmaf(zr[j + 6], ck[j + 6], a6);
            a7 = fmaf(zr[j + 7], ck[j + 7], a7);
        }
        const float dot = ((a0 + a1) + (a2 + a3)) + ((a4 + a5) + (a6 + a7));
        const float tkv = zsq + esq_lds[k0 + kk];
        const float m = 2.0f * dot;
        const float d = tkv - m;
        if (d < dmin) {   // strict <: lowest k wins ties, like np.argmin
            dmin = d;
            best = k0 + kk;
        }
    }

    // Combine the two k-halves. Upper half publishes, lower half reduces.
    if (t >= ROWS_PER_BLOCK) {
        red_d[tr] = dmin;
        red_b[tr] = best;
    }
    __syncthreads();
    if (t < ROWS_PER_BLOCK) {
        // strict <: on ties the lower-k half (this thread) wins, matching
        // global first-index argmin semantics.
        int b = (red_d[tr] < dmin) ? red_b[tr] : best;
        best_lds[tr] = b;
    }
    __syncthreads();

    // Block-cooperative coalesced write of both outputs.
    // 128 rows x 16 float4 = 2048 float4 stores per output stream;
    // consecutive threads write consecutive float4s -> fully coalesced.
    const float4* cb4 = (const float4*)cb;
    float4* o = (float4*)out;
    const size_t out1_off = (size_t)n_rows * (DIM / 4);
    const size_t grow = (size_t)blockIdx.x * ROWS_PER_BLOCK * (DIM / 4);
#pragma unroll
    for (int i = t; i < ROWS_PER_BLOCK * (DIM / 4); i += 256) {
        const int r = i >> 4;
        const int j = i & 15;
        const float4 v = cb4[(size_t)best_lds[r] * (DIM / 4) + j];
        const size_t g = grow + (size_t)r * (DIM / 4) + j;
        o[g] = v;
        o[g + out1_off] = v;
    }
}

extern "C" void kernel_launch(void* const* d_in, const int* in_sizes, int n_in,
                              void* d_out, int out_size, void* d_ws, size_t ws_size,
                              hipStream_t stream) {
    const float* z  = (const float*)d_in[0];   // [N, 64] fp32
    const float* cb = (const float*)d_in[1];   // [512, 64] fp32
    float* out = (float*)d_out;                // [2 * N * 64] fp32

    const int n_rows = in_sizes[0] / DIM;      // 131072
    const int grid = n_rows / ROWS_PER_BLOCK;  // 1024 blocks of 256

    vq_argmin_gather<<<dim3(grid), dim3(256), 0, stream>>>(z, cb, out, n_rows);
}

// Round 3
// 229.212 us; speedup vs baseline: 1.5445x; 1.0060x over previous
//
#include <hip/hip_runtime.h>
#include <math.h>

#define K_CODES 512
#define DIM 64
#define ROWS_PER_BLOCK 128   // 256 threads: t<128 scan k[0,256), t>=128 scan k[256,512)

// numpy pairwise sum (n=64 path): 8 strided accumulators, sequential adds
// within each, then pairwise tree combine. Contract OFF so products round
// separately from adds (matches np: elementwise square then pairwise sum).
__device__ __forceinline__ float np_pairwise_sumsq(const float* v) {
#pragma clang fp contract(off)
    float p[DIM];
#pragma unroll
    for (int j = 0; j < DIM; ++j) p[j] = v[j] * v[j];
    float r[8];
#pragma unroll
    for (int a = 0; a < 8; ++a) r[a] = p[a];
#pragma unroll
    for (int i = 8; i < DIM; i += 8) {
#pragma unroll
        for (int a = 0; a < 8; ++a) r[a] = r[a] + p[i + a];
    }
    return ((r[0] + r[1]) + (r[2] + r[3])) + ((r[4] + r[5]) + (r[6] + r[7]));
}

// launch_bounds(256, 4): 4 waves/EU -> VGPR cap 128. Kernel needs ~100
// (64 zr + 8 acc + addressing). Round-2 showed VGPR=48: the compiler
// rematerialized zr as per-kk global re-loads (L1-hot, invisible in
// FETCH_SIZE) -> L1-BW-bound at VALUBusy 48%. The asm barrier below makes
// zr opaque so it CANNOT be rematerialized and must stay in VGPRs.
__global__ __launch_bounds__(256, 4) void vq_argmin_gather(
    const float* __restrict__ z, const float* __restrict__ cb,
    float* __restrict__ out, int n_rows) {
#pragma clang fp contract(off)
    __shared__ float esq_lds[K_CODES];
    __shared__ float red_d[ROWS_PER_BLOCK];
    __shared__ int   red_b[ROWS_PER_BLOCK];
    __shared__ int   best_lds[ROWS_PER_BLOCK];

    const int t = threadIdx.x;

    const int tr  = t & (ROWS_PER_BLOCK - 1);            // row within block
    const int row = blockIdx.x * ROWS_PER_BLOCK + tr;
    // k-offset: 0 for threads 0..127, 256 for 128..255. Wave-uniform;
    // readfirstlane forces SGPR so codebook loads stay on the s_load path.
    const int k0 = __builtin_amdgcn_readfirstlane((t >> 7) << 8);

    // z row into 64 VGPRs (issue loads before esq work to overlap latency).
    float zr[DIM];
    const float4* zp = (const float4*)(z + (size_t)row * DIM);
#pragma unroll
    for (int j = 0; j < DIM / 4; ++j) {
        float4 v = zp[j];
        zr[4 * j + 0] = v.x;
        zr[4 * j + 1] = v.y;
        zr[4 * j + 2] = v.z;
        zr[4 * j + 3] = v.w;
    }
    // Residency barrier: values become opaque asm outputs -> the compiler
    // cannot re-load them from z later; they must live in VGPRs.
#pragma unroll
    for (int j = 0; j < DIM; ++j) {
        asm volatile("" : "+v"(zr[j]));
    }

    // esq for all 512 codes, numpy summation order (2 codes/thread).
    for (int c = t; c < K_CODES; c += 256) {
        esq_lds[c] = np_pairwise_sumsq(cb + (size_t)c * DIM);
    }
    __syncthreads();

    const float zsq = np_pairwise_sumsq(zr);

    float dmin = INFINITY;
    int best = k0;

    const float* __restrict__ cbase = cb + (size_t)k0 * DIM;
#pragma unroll 2
    for (int kk = 0; kk < K_CODES / 2; ++kk) {
        const float* __restrict__ ck = cbase + (size_t)kk * DIM;
        // 8-accumulator fmaf dot, tree combine -- IDENTICAL arithmetic to
        // the round-1/2 kernels that matched np argmin exactly. Do not alter.
        float a0 = 0.f, a1 = 0.f, a2 = 0.f, a3 = 0.f;
        float a4 = 0.f, a5 = 0.f, a6 = 0.f, a7 = 0.f;
#pragma unroll
        for (int j = 0; j < DIM; j += 8) {
            a0 = fmaf(zr[j + 0], ck[j + 0], a0);
            a1 = fmaf(zr[j + 1], ck[j + 1], a1);
            a2 = fmaf(zr[j + 2], ck[j + 2], a2);
            a3 = fmaf(zr[j + 3], ck[j + 3], a3);
            a4 = fmaf(zr[j + 4], ck[j + 4], a4);
            a5 = fmaf(zr[j + 5], ck[j + 5], a5);
            a6 = fmaf(zr[j + 6], ck[j + 6], a6);
            a7 = fmaf(zr[j + 7], ck[j + 7], a7);
        }
        const float dot = ((a0 + a1) + (a2 + a3)) + ((a4 + a5) + (a6 + a7));
        const float tkv = zsq + esq_lds[k0 + kk];
        const float m = 2.0f * dot;
        const float d = tkv - m;
        if (d < dmin) {   // strict <: lowest k wins ties, like np.argmin
            dmin = d;
            best = k0 + kk;
        }
    }

    // Combine the two k-halves. Upper half publishes, lower half reduces.
    if (t >= ROWS_PER_BLOCK) {
        red_d[tr] = dmin;
        red_b[tr] = best;
    }
    __syncthreads();
    if (t < ROWS_PER_BLOCK) {
        // strict <: on ties the lower-k half (this thread) wins, matching
        // global first-index argmin semantics.
        int b = (red_d[tr] < dmin) ? red_b[tr] : best;
        best_lds[tr] = b;
    }
    __syncthreads();

    // Block-cooperative coalesced write of both outputs.
    const float4* cb4 = (const float4*)cb;
    float4* o = (float4*)out;
    const size_t out1_off = (size_t)n_rows * (DIM / 4);
    const size_t grow = (size_t)blockIdx.x * ROWS_PER_BLOCK * (DIM / 4);
#pragma unroll
    for (int i = t; i < ROWS_PER_BLOCK * (DIM / 4); i += 256) {
        const int r = i >> 4;
        const int j = i & 15;
        const float4 v = cb4[(size_t)best_lds[r] * (DIM / 4) + j];
        const size_t g = grow + (size_t)r * (DIM / 4) + j;
        o[g] = v;
        o[g + out1_off] = v;
    }
}

extern "C" void kernel_launch(void* const* d_in, const int* in_sizes, int n_in,
                              void* d_out, int out_size, void* d_ws, size_t ws_size,
                              hipStream_t stream) {
    const float* z  = (const float*)d_in[0];   // [N, 64] fp32
    const float* cb = (const float*)d_in[1];   // [512, 64] fp32
    float* out = (float*)d_out;                // [2 * N * 64] fp32

    const int n_rows = in_sizes[0] / DIM;      // 131072
    const int grid = n_rows / ROWS_PER_BLOCK;  // 1024 blocks of 256

    vq_argmin_gather<<<dim3(grid), dim3(256), 0, stream>>>(z, cb, out, n_rows);
}